// Round 8
// baseline (443.668 us; speedup 1.0000x reference)
//
#include <hip/hip_runtime.h>
#include <hip/hip_bf16.h>

// CausalMHA fused: x@Wqkv -> causal flash attention -> @Wout
// B=2 S=2048 D=2048 H=16 Dh=128.
// R5: 8-phase 256x256 GEMM fixed — phases partition LDS halves (phase (MH,NH)
//     reads only A-half MH / B-half NH), staging strictly 1 tile ahead into
//     the idle parity buffer, uniform vmcnt(4) ledger. R4's bug: staged t+2
//     into the live buffer while every phase still read it.
// Attention unchanged from R2 (pair-balanced).

#define SEQ 2048
#define DM 2048
#define NQKV 6144
#define DH 128

typedef __attribute__((ext_vector_type(8))) short bf16x8;
typedef __attribute__((ext_vector_type(4))) float f32x4;

__device__ __forceinline__ f32x4 mfma16(bf16x8 a, bf16x8 b, f32x4 c) {
  return __builtin_amdgcn_mfma_f32_16x16x32_bf16(a, b, c, 0, 0, 0);
}

__device__ __forceinline__ void gload_lds16(const void* g, void* l) {
  __builtin_amdgcn_global_load_lds(
      (const __attribute__((address_space(1))) unsigned int*)g,
      (__attribute__((address_space(3))) unsigned int*)l, 16, 0, 0);
}

// ---------------- cast fp32 -> bf16, 4 elems/thread ----------------
__global__ __launch_bounds__(256) void cast_f32_bf16(
    const float* __restrict__ in, __hip_bfloat16* __restrict__ out, int n4) {
  int i = blockIdx.x * 256 + threadIdx.x;
  if (i >= n4) return;
  float4 f = reinterpret_cast<const float4*>(in)[i];
  union { __hip_bfloat16 h[4]; unsigned long long u; } o;
  o.h[0] = __float2bfloat16(f.x); o.h[1] = __float2bfloat16(f.y);
  o.h[2] = __float2bfloat16(f.z); o.h[3] = __float2bfloat16(f.w);
  reinterpret_cast<unsigned long long*>(out)[i] = o.u;
}

// ------------- transpose + cast: fp32 [R][C] -> bf16 [C][R] -------------
__global__ __launch_bounds__(256) void transpose_cast(
    const float* __restrict__ in, __hip_bfloat16* __restrict__ out, int R, int C) {
  __shared__ float t[32][33];
  int c0 = blockIdx.x * 32, r0 = blockIdx.y * 32;
  int tx = threadIdx.x, ty = threadIdx.y;
#pragma unroll
  for (int i = 0; i < 4; ++i)
    t[ty + i * 8][tx] = in[(size_t)(r0 + ty + i * 8) * C + c0 + tx];
  __syncthreads();
#pragma unroll
  for (int i = 0; i < 4; ++i)
    out[(size_t)(c0 + ty + i * 8) * R + r0 + tx] = __float2bfloat16(t[tx][ty + i * 8]);
}

// ---- transpose V region of qkv [b,s,(2*DM+h*DH+d)] -> vT[(b*16+h)*128+d][s] ----
__global__ __launch_bounds__(256) void transpose_v(
    const __hip_bfloat16* __restrict__ qkv, __hip_bfloat16* __restrict__ vT) {
  __shared__ __hip_bfloat16 t[32][33];
  int bh = blockIdx.z;
  int b = bh >> 4, h = bh & 15;
  int s0 = blockIdx.x * 32, d0 = blockIdx.y * 32;
  int tx = threadIdx.x, ty = threadIdx.y;
#pragma unroll
  for (int i = 0; i < 4; ++i)
    t[ty + i * 8][tx] =
        qkv[(size_t)(b * SEQ + s0 + ty + i * 8) * NQKV + 2 * DM + h * DH + d0 + tx];
  __syncthreads();
#pragma unroll
  for (int i = 0; i < 4; ++i)
    vT[(size_t)(bh * DH + d0 + ty + i * 8) * SEQ + s0 + tx] = t[tx][ty + i * 8];
}

// ============ 256x256 8-phase GEMM: C = A[M][K] * Bt[N][K]^T ============
// 8 waves (2M x 4N), 512 thr, BK=64, LDS 128 KiB (2-dbuf x {A,B} x 2 halves).
// Interleaved wave map: phase (MH,NH) reads ONLY A-half MH and B-half NH:
//   C row = bm0 + MH*128 + wm*64 + mf*16 + lg*4+j  (mi = MH*4+mf)
//   C col = bn0 + NH*128 + wn*32 + nf*16 + lr      (ni = NH*2+nf)
// Stage (tile t): ph1->A0(t+1), ph2->B0(t+1), ph3->B1(t+1), ph4->A1(t+1),
// always into buffer (t+1)&1 (idle this tile -> write-safe).
// vmcnt ledger (2 loads/STAGE, FIFO): vmcnt(4) before BAR1 each phase forces
// exactly the half first-read next phase; tail tile uses vmcnt(2)/vmcnt(0).
// LDS swizzle: 16B-slot ^= (row&7) on write-source and read (rule #21).
template <int EPI>
__global__ __launch_bounds__(512, 2) void gemm256(
    const __hip_bfloat16* __restrict__ A, const __hip_bfloat16* __restrict__ Bt,
    void* __restrict__ Cout, int M, int N, int K) {
  __shared__ alignas(16) char lds[131072];  // A @0, B @65536
  const int tid = threadIdx.x;
  const int lane = tid & 63, w = tid >> 6;
  const int wm = w >> 2, wn = w & 3;
  const int lr = lane & 15, lg = lane >> 4;
  const int nbn = N >> 8;
  const int cpx = gridDim.x >> 3;  // gridDim.x % 8 == 0
  const int swz = (blockIdx.x & 7) * cpx + (blockIdx.x >> 3);
  const size_t bm0 = (size_t)(swz / nbn) << 8;
  const size_t bn0 = (size_t)(swz % nbn) << 8;
  const int nt = K >> 6;

  // staging: thread covers rows r0, r0+64 of a [128][64] half-tile
  const int r0 = tid >> 3;
  const int scol = ((tid & 7) ^ (r0 & 7)) * 8;  // inverse-swizzled src slot
  // ds-read constants (row&7 == lr&7 for all fragments)
  const int laneA = wm * 8192 + lr * 128;
  const int laneB = wn * 4096 + lr * 128;
  const int s0 = (lg ^ (lr & 7)) * 16;
  const int s1 = ((4 + lg) ^ (lr & 7)) * 16;

  f32x4 acc[8][4] = {};

  // which: 0=A-half0, 1=A-half1, 2=B-half0, 3=B-half1
  auto STAGE = [&](int which, int kt) {
    char* dst = lds + (which >> 1) * 65536 + (kt & 1) * 32768 +
                (which & 1) * 16384 + tid * 16;
    const __hip_bfloat16* src = (which >= 2) ? Bt : A;
    size_t rbase = ((which >= 2) ? bn0 : bm0) + (size_t)((which & 1) * 128);
    int kc = kt * 64 + scol;
#pragma unroll
    for (int i = 0; i < 2; ++i)
      gload_lds16(src + (rbase + r0 + i * 64) * K + kc, dst + i * 8192);
  };

  // VMTAIL: vmcnt immediate for the last tile (-1 = none)
#define PHASE(MH, NH, STW, VMTAIL)                                             \
  do {                                                                         \
    const int par = (t & 1) * 32768;                                           \
    bf16x8 af[4][2], bq[2][2];                                                 \
    _Pragma("unroll") for (int mf = 0; mf < 4; ++mf) {                         \
      const char* ab = lds + par + (MH)*16384 + laneA + mf * 2048;             \
      af[mf][0] = *(const bf16x8*)(ab + s0);                                   \
      af[mf][1] = *(const bf16x8*)(ab + s1);                                   \
    }                                                                          \
    _Pragma("unroll") for (int nf = 0; nf < 2; ++nf) {                         \
      const char* bb = lds + 65536 + par + (NH)*16384 + laneB + nf * 2048;     \
      bq[nf][0] = *(const bf16x8*)(bb + s0);                                   \
      bq[nf][1] = *(const bf16x8*)(bb + s1);                                   \
    }                                                                          \
    if (t + 1 < nt) {                                                          \
      STAGE(STW, t + 1);                                                       \
      asm volatile("s_waitcnt vmcnt(4)" ::: "memory");                         \
    } else if ((VMTAIL) == 2) {                                                \
      asm volatile("s_waitcnt vmcnt(2)" ::: "memory");                         \
    } else if ((VMTAIL) == 0) {                                                \
      asm volatile("s_waitcnt vmcnt(0)" ::: "memory");                         \
    }                                                                          \
    __builtin_amdgcn_s_barrier();                                              \
    __builtin_amdgcn_sched_barrier(0);                                         \
    __builtin_amdgcn_s_setprio(1);                                             \
    _Pragma("unroll") for (int ks = 0; ks < 2; ++ks)                           \
        _Pragma("unroll") for (int mf = 0; mf < 4; ++mf)                       \
        _Pragma("unroll") for (int nf = 0; nf < 2; ++nf)                       \
            acc[(MH)*4 + mf][(NH)*2 + nf] = mfma16(                            \
            af[mf][ks], bq[nf][ks], acc[(MH)*4 + mf][(NH)*2 + nf]);            \
    __builtin_amdgcn_s_setprio(0);                                             \
    __builtin_amdgcn_sched_barrier(0);                                         \
    __builtin_amdgcn_s_barrier();                                              \
  } while (0)

  // prologue: stage all of tile 0; keep B1(0),A1(0) in flight
  STAGE(0, 0); STAGE(2, 0); STAGE(3, 0); STAGE(1, 0);
  asm volatile("s_waitcnt vmcnt(4)" ::: "memory");
  __builtin_amdgcn_s_barrier();

  for (int t = 0; t < nt; ++t) {
    PHASE(0, 0, 0, 2);   // reads A0,B0; stages A0(t+1); tail: force B1(t)
    PHASE(0, 1, 2, 0);   // reads A0,B1; stages B0(t+1); tail: force A1(t)
    PHASE(1, 0, 3, -1);  // reads A1,B0; stages B1(t+1)
    PHASE(1, 1, 1, -1);  // reads A1,B1; stages A1(t+1)
  }
#undef PHASE

#pragma unroll
  for (int mi = 0; mi < 8; ++mi)
#pragma unroll
    for (int ni = 0; ni < 4; ++ni)
#pragma unroll
      for (int j = 0; j < 4; ++j) {
        size_t r = bm0 + (mi >> 2) * 128 + wm * 64 + (mi & 3) * 16 + lg * 4 + j;
        size_t c = bn0 + (ni >> 1) * 128 + wn * 32 + (ni & 1) * 16 + lr;
        if (EPI == 0)
          ((__hip_bfloat16*)Cout)[r * N + c] = __float2bfloat16(acc[mi][ni][j]);
        else
          ((float*)Cout)[r * N + c] = acc[mi][ni][j];
      }
}

// ---------------- causal flash attention (pair-balanced, KVBLK=128) ----------------
__device__ __forceinline__ void attn_tile(
    const bf16x8 (&qf)[4], f32x4 (&of)[8], float (&mrun)[4], float (&lrun)[4],
    const char* Ks, const char* Vs, char* pw,
    int lr, int lg, int kv0, int myq, bool lastmask, float scale) {
  f32x4 sacc[8];
#pragma unroll
  for (int n = 0; n < 8; ++n) sacc[n] = f32x4{0.f, 0.f, 0.f, 0.f};
#pragma unroll
  for (int n = 0; n < 8; ++n) {
    const int krow = n * 16 + lr;
    const char* kbase = Ks + krow * 256;
#pragma unroll
    for (int ks = 0; ks < 4; ++ks) {
      int c = ks * 64 + lg * 16;
      bf16x8 kb = *(const bf16x8*)(kbase + (c ^ ((krow & 7) << 4)));
      sacc[n] = mfma16(qf[ks], kb, sacc[n]);
    }
  }
#pragma unroll
  for (int n = 0; n < 8; ++n)
#pragma unroll
    for (int j = 0; j < 4; ++j) {
      float v = sacc[n][j] * scale;
      if (lastmask && (kv0 + n * 16 + lr > myq + j)) v = -1e30f;
      sacc[n][j] = v;
    }
  float pm[4];
#pragma unroll
  for (int j = 0; j < 4; ++j) {
    float a = fmaxf(fmaxf(sacc[0][j], sacc[1][j]), fmaxf(sacc[2][j], sacc[3][j]));
    float bx = fmaxf(fmaxf(sacc[4][j], sacc[5][j]), fmaxf(sacc[6][j], sacc[7][j]));
    pm[j] = fmaxf(a, bx);
  }
#pragma unroll
  for (int d = 1; d < 16; d <<= 1)
#pragma unroll
    for (int j = 0; j < 4; ++j) pm[j] = fmaxf(pm[j], __shfl_xor(pm[j], d));
  bool big = false;
#pragma unroll
  for (int j = 0; j < 4; ++j) big = big || (pm[j] > mrun[j] + 8.0f);
  if (__any(big)) {
#pragma unroll
    for (int j = 0; j < 4; ++j) {
      float mn = fmaxf(mrun[j], pm[j]);
      float corr = __expf(mrun[j] - mn);
      mrun[j] = mn;
      lrun[j] *= corr;
#pragma unroll
      for (int nn = 0; nn < 8; ++nn) of[nn][j] *= corr;
    }
  }
  float rs[4] = {0.f, 0.f, 0.f, 0.f};
#pragma unroll
  for (int n = 0; n < 8; ++n)
#pragma unroll
    for (int j = 0; j < 4; ++j) {
      float pv = __expf(sacc[n][j] - mrun[j]);
      sacc[n][j] = pv;
      rs[j] += pv;
    }
#pragma unroll
  for (int d = 1; d < 16; d <<= 1)
#pragma unroll
    for (int j = 0; j < 4; ++j) rs[j] += __shfl_xor(rs[j], d);
#pragma unroll
  for (int j = 0; j < 4; ++j) lrun[j] += rs[j];
#pragma unroll
  for (int j = 0; j < 4; ++j) {
    int prow = lg * 4 + j;
    char* pb = pw + prow * 256;
#pragma unroll
    for (int n = 0; n < 8; ++n) {
      int c = (n * 16 + lr) * 2;
      *(__hip_bfloat16*)(pb + (c ^ ((prow & 7) << 4))) = __float2bfloat16(sacc[n][j]);
    }
  }
#pragma unroll
  for (int kvs = 0; kvs < 4; ++kvs) {
    int c = kvs * 64 + lg * 16;
    bf16x8 pa = *(const bf16x8*)(pw + lr * 256 + (c ^ ((lr & 7) << 4)));
#pragma unroll
    for (int nn = 0; nn < 8; ++nn) {
      int vrow = nn * 16 + lr;
      bf16x8 vb = *(const bf16x8*)(Vs + vrow * 256 + (c ^ ((vrow & 7) << 4)));
      of[nn] = mfma16(pa, vb, of[nn]);
    }
  }
}

__global__ __launch_bounds__(256, 2) void attn_causal(
    const __hip_bfloat16* __restrict__ qkv, const __hip_bfloat16* __restrict__ vT,
    __hip_bfloat16* __restrict__ O) {
  __shared__ alignas(16) __hip_bfloat16 Ks[128 * 128];
  __shared__ alignas(16) __hip_bfloat16 Vs[128 * 128];
  __shared__ alignas(16) __hip_bfloat16 Ps[4][16 * 128];
  const int tid = threadIdx.x, lane = tid & 63, w = tid >> 6;
  const int lr = lane & 15, lg = lane >> 4;
  const int p = blockIdx.x, bh = blockIdx.y;
  const int b = bh >> 4, h = bh & 15;
  const int qtA = p, qtB = 31 - p;
  const int q0A = qtA * 64, q0B = qtB * 64;
  const int ntA = (qtA + 2) >> 1, ntB = (qtB + 2) >> 1;
  const float scale = 0.08838834764831845f;
  bf16x8 qfA[4], qfB[4];
  {
    const __hip_bfloat16* qpA =
        qkv + (size_t)(b * SEQ + q0A + w * 16 + lr) * NQKV + h * DH;
    const __hip_bfloat16* qpB =
        qkv + (size_t)(b * SEQ + q0B + w * 16 + lr) * NQKV + h * DH;
#pragma unroll
    for (int ks = 0; ks < 4; ++ks) {
      qfA[ks] = *(const bf16x8*)(qpA + ks * 32 + lg * 8);
      qfB[ks] = *(const bf16x8*)(qpB + ks * 32 + lg * 8);
    }
  }
  f32x4 ofA[8] = {}, ofB[8] = {};
  float mA[4], lA[4], mB[4], lB[4];
#pragma unroll
  for (int j = 0; j < 4; ++j) { mA[j] = mB[j] = -1e30f; lA[j] = lB[j] = 0.f; }
  const int myqA = q0A + w * 16 + lg * 4;
  const int myqB = q0B + w * 16 + lg * 4;
  char* pw = (char*)&Ps[w][0];

  for (int t = 0; t < ntB; ++t) {
    const int kv0 = t * 128;
#pragma unroll
    for (int it = 0; it < 8; ++it) {
      int g = it * 256 + tid;
      int r = g >> 4, sl = g & 15;
      int ssl = sl ^ (r & 7);
      gload_lds16(qkv + (size_t)(b * SEQ + kv0 + r) * NQKV + DM + h * DH + ssl * 8,
                  (char*)Ks + (size_t)g * 16);
    }
#pragma unroll
    for (int it = 0; it < 8; ++it) {
      int g = it * 256 + tid;
      int r = g >> 4, sl = g & 15;
      int ssl = sl ^ (r & 7);
      gload_lds16(vT + (size_t)(bh * DH + r) * SEQ + kv0 + ssl * 8,
                  (char*)Vs + (size_t)g * 16);
    }
    __syncthreads();
    if (t < ntA)
      attn_tile(qfA, ofA, mA, lA, (const char*)Ks, (const char*)Vs, pw,
                lr, lg, kv0, myqA, t == ntA - 1, scale);
    attn_tile(qfB, ofB, mB, lB, (const char*)Ks, (const char*)Vs, pw,
              lr, lg, kv0, myqB, t == ntB - 1, scale);
    __syncthreads();
  }
#pragma unroll
  for (int j = 0; j < 4; ++j) {
    float invA = 1.0f / lA[j], invB = 1.0f / lB[j];
    __hip_bfloat16* opA =
        O + (size_t)(b * SEQ + q0A + w * 16 + lg * 4 + j) * DM + h * DH;
    __hip_bfloat16* opB =
        O + (size_t)(b * SEQ + q0B + w * 16 + lg * 4 + j) * DM + h * DH;
#pragma unroll
    for (int nn = 0; nn < 8; ++nn) {
      opA[nn * 16 + lr] = __float2bfloat16(ofA[nn][j] * invA);
      opB[nn * 16 + lr] = __float2bfloat16(ofB[nn][j] * invB);
    }
  }
}

extern "C" void kernel_launch(void* const* d_in, const int* in_sizes, int n_in,
                              void* d_out, int out_size, void* d_ws, size_t ws_size,
                              hipStream_t stream) {
  const float* x = (const float*)d_in[0];
  const float* Wqkv = (const float*)d_in[1];
  const float* Wout = (const float*)d_in[2];
  float* out = (float*)d_out;
  char* ws = (char*)d_ws;
  __hip_bfloat16* xb    = (__hip_bfloat16*)(ws + 0);
  __hip_bfloat16* wqkvT = (__hip_bfloat16*)(ws + (size_t)16777216);
  __hip_bfloat16* woutT = (__hip_bfloat16*)(ws + (size_t)41943040);
  __hip_bfloat16* qkvb  = (__hip_bfloat16*)(ws + (size_t)50331648);
  __hip_bfloat16* vT    = (__hip_bfloat16*)(ws + (size_t)100663296);
  __hip_bfloat16* ob    = (__hip_bfloat16*)(ws + (size_t)117440512);

  cast_f32_bf16<<<dim3(8192), dim3(256), 0, stream>>>(x, xb, 8388608 / 4);
  transpose_cast<<<dim3(192, 64), dim3(32, 8), 0, stream>>>(Wqkv, wqkvT, 2048, 6144);
  transpose_cast<<<dim3(64, 64), dim3(32, 8), 0, stream>>>(Wout, woutT, 2048, 2048);
  gemm256<0><<<dim3(384), dim3(512), 0, stream>>>(xb, wqkvT, qkvb, 4096, 6144, 2048);
  transpose_v<<<dim3(64, 4, 32), dim3(32, 8), 0, stream>>>(qkvb, vT);
  attn_causal<<<dim3(16, 32), dim3(256), 0, stream>>>(qkvb, vT, ob);
  gemm256<1><<<dim3(128), dim3(512), 0, stream>>>(ob, woutT, out, 4096, 2048, 2048);
}

// Round 10
// 437.378 us; speedup vs baseline: 1.0144x; 1.0144x over previous
//
#include <hip/hip_runtime.h>
#include <hip/hip_bf16.h>

// CausalMHA fused: x@Wqkv -> causal flash attention -> @Wout
// B=2 S=2048 D=2048 H=16 Dh=128.
// R9: wait-ledger refinement on the 8-phase GEMM. R8 measured MfmaUtil 29%
//     (conflicts 0): per-phase vmcnt forced loads only ~2 phases old -> stall
//     every phase. New ledger: waits at ph2(6)/ph3(6)/ph4(4) only, forced
//     ages >=2 (mostly 3) phases; ph1 has no wait. Tail: ph2(2)/ph3(0).
// Attention unchanged from R2 (pair-balanced).

#define SEQ 2048
#define DM 2048
#define NQKV 6144
#define DH 128

typedef __attribute__((ext_vector_type(8))) short bf16x8;
typedef __attribute__((ext_vector_type(4))) float f32x4;

__device__ __forceinline__ f32x4 mfma16(bf16x8 a, bf16x8 b, f32x4 c) {
  return __builtin_amdgcn_mfma_f32_16x16x32_bf16(a, b, c, 0, 0, 0);
}

__device__ __forceinline__ void gload_lds16(const void* g, void* l) {
  __builtin_amdgcn_global_load_lds(
      (const __attribute__((address_space(1))) unsigned int*)g,
      (__attribute__((address_space(3))) unsigned int*)l, 16, 0, 0);
}

// ---------------- cast fp32 -> bf16, 4 elems/thread ----------------
__global__ __launch_bounds__(256) void cast_f32_bf16(
    const float* __restrict__ in, __hip_bfloat16* __restrict__ out, int n4) {
  int i = blockIdx.x * 256 + threadIdx.x;
  if (i >= n4) return;
  float4 f = reinterpret_cast<const float4*>(in)[i];
  union { __hip_bfloat16 h[4]; unsigned long long u; } o;
  o.h[0] = __float2bfloat16(f.x); o.h[1] = __float2bfloat16(f.y);
  o.h[2] = __float2bfloat16(f.z); o.h[3] = __float2bfloat16(f.w);
  reinterpret_cast<unsigned long long*>(out)[i] = o.u;
}

// ------------- transpose + cast: fp32 [R][C] -> bf16 [C][R] -------------
__global__ __launch_bounds__(256) void transpose_cast(
    const float* __restrict__ in, __hip_bfloat16* __restrict__ out, int R, int C) {
  __shared__ float t[32][33];
  int c0 = blockIdx.x * 32, r0 = blockIdx.y * 32;
  int tx = threadIdx.x, ty = threadIdx.y;
#pragma unroll
  for (int i = 0; i < 4; ++i)
    t[ty + i * 8][tx] = in[(size_t)(r0 + ty + i * 8) * C + c0 + tx];
  __syncthreads();
#pragma unroll
  for (int i = 0; i < 4; ++i)
    out[(size_t)(c0 + ty + i * 8) * R + r0 + tx] = __float2bfloat16(t[tx][ty + i * 8]);
}

// ---- transpose V region of qkv [b,s,(2*DM+h*DH+d)] -> vT[(b*16+h)*128+d][s] ----
__global__ __launch_bounds__(256) void transpose_v(
    const __hip_bfloat16* __restrict__ qkv, __hip_bfloat16* __restrict__ vT) {
  __shared__ __hip_bfloat16 t[32][33];
  int bh = blockIdx.z;
  int b = bh >> 4, h = bh & 15;
  int s0 = blockIdx.x * 32, d0 = blockIdx.y * 32;
  int tx = threadIdx.x, ty = threadIdx.y;
#pragma unroll
  for (int i = 0; i < 4; ++i)
    t[ty + i * 8][tx] =
        qkv[(size_t)(b * SEQ + s0 + ty + i * 8) * NQKV + 2 * DM + h * DH + d0 + tx];
  __syncthreads();
#pragma unroll
  for (int i = 0; i < 4; ++i)
    vT[(size_t)(bh * DH + d0 + ty + i * 8) * SEQ + s0 + tx] = t[tx][ty + i * 8];
}

// ============ 256x256 8-phase GEMM: C = A[M][K] * Bt[N][K]^T ============
// 8 waves (2M x 4N), 512 thr, BK=64, LDS 128 KiB (2-dbuf x {A,B} x 2 halves).
// Interleaved wave map: phase (MH,NH) reads ONLY A-half MH and B-half NH.
// Phase first-reads: ph1{A0,B0} ph2{B1} ph3{A1} ph4{}.
// Stage (tile t): ph1->A0(t+1), ph2->B0(t+1), ph3->B1(t+1), ph4->A1(t+1),
// always into buffer (t+1)&1 (idle this tile -> write-safe).
// Wait ledger (2 loads/half, FIFO; steady-state queue peaks at 8):
//   ph1: none   ph2: vmcnt(6)->B1(t) age3   ph3: vmcnt(6)->A1(t) age3
//   ph4: vmcnt(4)->A0,B0(t+1) ages 3/2.  Tail tile: ph2(2), ph3(0).
// LDS swizzle: 16B-slot ^= (row&7) on write-source and read (rule #21).
template <int EPI>
__global__ __launch_bounds__(512, 2) void gemm256(
    const __hip_bfloat16* __restrict__ A, const __hip_bfloat16* __restrict__ Bt,
    void* __restrict__ Cout, int M, int N, int K) {
  __shared__ alignas(16) char lds[131072];  // A @0, B @65536
  const int tid = threadIdx.x;
  const int lane = tid & 63, w = tid >> 6;
  const int wm = w >> 2, wn = w & 3;
  const int lr = lane & 15, lg = lane >> 4;
  const int nbn = N >> 8;
  const int cpx = gridDim.x >> 3;  // gridDim.x % 8 == 0
  const int swz = (blockIdx.x & 7) * cpx + (blockIdx.x >> 3);
  const size_t bm0 = (size_t)(swz / nbn) << 8;
  const size_t bn0 = (size_t)(swz % nbn) << 8;
  const int nt = K >> 6;

  // staging: thread covers rows r0, r0+64 of a [128][64] half-tile
  const int r0 = tid >> 3;
  const int scol = ((tid & 7) ^ (r0 & 7)) * 8;  // inverse-swizzled src slot
  // ds-read constants (row&7 == lr&7 for all fragments)
  const int laneA = wm * 8192 + lr * 128;
  const int laneB = wn * 4096 + lr * 128;
  const int s0 = (lg ^ (lr & 7)) * 16;
  const int s1 = ((4 + lg) ^ (lr & 7)) * 16;

  f32x4 acc[8][4] = {};

  // which: 0=A-half0, 1=A-half1, 2=B-half0, 3=B-half1
  auto STAGE = [&](int which, int kt) {
    char* dst = lds + (which >> 1) * 65536 + (kt & 1) * 32768 +
                (which & 1) * 16384 + tid * 16;
    const __hip_bfloat16* src = (which >= 2) ? Bt : A;
    size_t rbase = ((which >= 2) ? bn0 : bm0) + (size_t)((which & 1) * 128);
    int kc = kt * 64 + scol;
#pragma unroll
    for (int i = 0; i < 2; ++i)
      gload_lds16(src + (rbase + r0 + i * 64) * K + kc, dst + i * 8192);
  };

  // VMS: steady-state vmcnt N (-1 = no wait). VMT: tail-tile vmcnt N (-1 none).
#define PHASE(MH, NH, STW, VMS, VMT)                                           \
  do {                                                                         \
    const int par = (t & 1) * 32768;                                           \
    bf16x8 af[4][2], bq[2][2];                                                 \
    _Pragma("unroll") for (int mf = 0; mf < 4; ++mf) {                         \
      const char* ab = lds + par + (MH)*16384 + laneA + mf * 2048;             \
      af[mf][0] = *(const bf16x8*)(ab + s0);                                   \
      af[mf][1] = *(const bf16x8*)(ab + s1);                                   \
    }                                                                          \
    _Pragma("unroll") for (int nf = 0; nf < 2; ++nf) {                         \
      const char* bb = lds + 65536 + par + (NH)*16384 + laneB + nf * 2048;     \
      bq[nf][0] = *(const bf16x8*)(bb + s0);                                   \
      bq[nf][1] = *(const bf16x8*)(bb + s1);                                   \
    }                                                                          \
    if (t + 1 < nt) {                                                          \
      STAGE(STW, t + 1);                                                       \
      if ((VMS) >= 0)                                                          \
        asm volatile("s_waitcnt vmcnt(" #VMS ")" ::: "memory");                \
    } else if ((VMT) >= 0) {                                                   \
      asm volatile("s_waitcnt vmcnt(" #VMT ")" ::: "memory");                  \
    }                                                                          \
    __builtin_amdgcn_s_barrier();                                              \
    __builtin_amdgcn_sched_barrier(0);                                         \
    __builtin_amdgcn_s_setprio(1);                                             \
    _Pragma("unroll") for (int ks = 0; ks < 2; ++ks)                           \
        _Pragma("unroll") for (int mf = 0; mf < 4; ++mf)                       \
        _Pragma("unroll") for (int nf = 0; nf < 2; ++nf)                       \
            acc[(MH)*4 + mf][(NH)*2 + nf] = mfma16(                            \
            af[mf][ks], bq[nf][ks], acc[(MH)*4 + mf][(NH)*2 + nf]);            \
    __builtin_amdgcn_s_setprio(0);                                             \
    __builtin_amdgcn_sched_barrier(0);                                         \
    __builtin_amdgcn_s_barrier();                                              \
  } while (0)

  // prologue: stage all of tile 0; keep B1(0),A1(0) in flight
  STAGE(0, 0); STAGE(2, 0); STAGE(3, 0); STAGE(1, 0);
  asm volatile("s_waitcnt vmcnt(4)" ::: "memory");
  __builtin_amdgcn_s_barrier();

  for (int t = 0; t < nt; ++t) {
    PHASE(0, 0, 0, -1, -1);  // reads A0,B0; stages A0(t+1); no wait
    PHASE(0, 1, 2, 6, 2);    // reads A0,B1; stages B0(t+1); force B1(t)
    PHASE(1, 0, 3, 6, 0);    // reads A1,B0; stages B1(t+1); force A1(t)
    PHASE(1, 1, 1, 4, -1);   // reads A1,B1; stages A1(t+1); force A0,B0(t+1)
  }
#undef PHASE

#pragma unroll
  for (int mi = 0; mi < 8; ++mi)
#pragma unroll
    for (int ni = 0; ni < 4; ++ni)
#pragma unroll
      for (int j = 0; j < 4; ++j) {
        size_t r = bm0 + (mi >> 2) * 128 + wm * 64 + (mi & 3) * 16 + lg * 4 + j;
        size_t c = bn0 + (ni >> 1) * 128 + wn * 32 + (ni & 1) * 16 + lr;
        if (EPI == 0)
          ((__hip_bfloat16*)Cout)[r * N + c] = __float2bfloat16(acc[mi][ni][j]);
        else
          ((float*)Cout)[r * N + c] = acc[mi][ni][j];
      }
}

// ---------------- causal flash attention (pair-balanced, KVBLK=128) ----------------
__device__ __forceinline__ void attn_tile(
    const bf16x8 (&qf)[4], f32x4 (&of)[8], float (&mrun)[4], float (&lrun)[4],
    const char* Ks, const char* Vs, char* pw,
    int lr, int lg, int kv0, int myq, bool lastmask, float scale) {
  f32x4 sacc[8];
#pragma unroll
  for (int n = 0; n < 8; ++n) sacc[n] = f32x4{0.f, 0.f, 0.f, 0.f};
#pragma unroll
  for (int n = 0; n < 8; ++n) {
    const int krow = n * 16 + lr;
    const char* kbase = Ks + krow * 256;
#pragma unroll
    for (int ks = 0; ks < 4; ++ks) {
      int c = ks * 64 + lg * 16;
      bf16x8 kb = *(const bf16x8*)(kbase + (c ^ ((krow & 7) << 4)));
      sacc[n] = mfma16(qf[ks], kb, sacc[n]);
    }
  }
#pragma unroll
  for (int n = 0; n < 8; ++n)
#pragma unroll
    for (int j = 0; j < 4; ++j) {
      float v = sacc[n][j] * scale;
      if (lastmask && (kv0 + n * 16 + lr > myq + j)) v = -1e30f;
      sacc[n][j] = v;
    }
  float pm[4];
#pragma unroll
  for (int j = 0; j < 4; ++j) {
    float a = fmaxf(fmaxf(sacc[0][j], sacc[1][j]), fmaxf(sacc[2][j], sacc[3][j]));
    float bx = fmaxf(fmaxf(sacc[4][j], sacc[5][j]), fmaxf(sacc[6][j], sacc[7][j]));
    pm[j] = fmaxf(a, bx);
  }
#pragma unroll
  for (int d = 1; d < 16; d <<= 1)
#pragma unroll
    for (int j = 0; j < 4; ++j) pm[j] = fmaxf(pm[j], __shfl_xor(pm[j], d));
  bool big = false;
#pragma unroll
  for (int j = 0; j < 4; ++j) big = big || (pm[j] > mrun[j] + 8.0f);
  if (__any(big)) {
#pragma unroll
    for (int j = 0; j < 4; ++j) {
      float mn = fmaxf(mrun[j], pm[j]);
      float corr = __expf(mrun[j] - mn);
      mrun[j] = mn;
      lrun[j] *= corr;
#pragma unroll
      for (int nn = 0; nn < 8; ++nn) of[nn][j] *= corr;
    }
  }
  float rs[4] = {0.f, 0.f, 0.f, 0.f};
#pragma unroll
  for (int n = 0; n < 8; ++n)
#pragma unroll
    for (int j = 0; j < 4; ++j) {
      float pv = __expf(sacc[n][j] - mrun[j]);
      sacc[n][j] = pv;
      rs[j] += pv;
    }
#pragma unroll
  for (int d = 1; d < 16; d <<= 1)
#pragma unroll
    for (int j = 0; j < 4; ++j) rs[j] += __shfl_xor(rs[j], d);
#pragma unroll
  for (int j = 0; j < 4; ++j) lrun[j] += rs[j];
#pragma unroll
  for (int j = 0; j < 4; ++j) {
    int prow = lg * 4 + j;
    char* pb = pw + prow * 256;
#pragma unroll
    for (int n = 0; n < 8; ++n) {
      int c = (n * 16 + lr) * 2;
      *(__hip_bfloat16*)(pb + (c ^ ((prow & 7) << 4))) = __float2bfloat16(sacc[n][j]);
    }
  }
#pragma unroll
  for (int kvs = 0; kvs < 4; ++kvs) {
    int c = kvs * 64 + lg * 16;
    bf16x8 pa = *(const bf16x8*)(pw + lr * 256 + (c ^ ((lr & 7) << 4)));
#pragma unroll
    for (int nn = 0; nn < 8; ++nn) {
      int vrow = nn * 16 + lr;
      bf16x8 vb = *(const bf16x8*)(Vs + vrow * 256 + (c ^ ((vrow & 7) << 4)));
      of[nn] = mfma16(pa, vb, of[nn]);
    }
  }
}

__global__ __launch_bounds__(256, 2) void attn_causal(
    const __hip_bfloat16* __restrict__ qkv, const __hip_bfloat16* __restrict__ vT,
    __hip_bfloat16* __restrict__ O) {
  __shared__ alignas(16) __hip_bfloat16 Ks[128 * 128];
  __shared__ alignas(16) __hip_bfloat16 Vs[128 * 128];
  __shared__ alignas(16) __hip_bfloat16 Ps[4][16 * 128];
  const int tid = threadIdx.x, lane = tid & 63, w = tid >> 6;
  const int lr = lane & 15, lg = lane >> 4;
  const int p = blockIdx.x, bh = blockIdx.y;
  const int b = bh >> 4, h = bh & 15;
  const int qtA = p, qtB = 31 - p;
  const int q0A = qtA * 64, q0B = qtB * 64;
  const int ntA = (qtA + 2) >> 1, ntB = (qtB + 2) >> 1;
  const float scale = 0.08838834764831845f;
  bf16x8 qfA[4], qfB[4];
  {
    const __hip_bfloat16* qpA =
        qkv + (size_t)(b * SEQ + q0A + w * 16 + lr) * NQKV + h * DH;
    const __hip_bfloat16* qpB =
        qkv + (size_t)(b * SEQ + q0B + w * 16 + lr) * NQKV + h * DH;
#pragma unroll
    for (int ks = 0; ks < 4; ++ks) {
      qfA[ks] = *(const bf16x8*)(qpA + ks * 32 + lg * 8);
      qfB[ks] = *(const bf16x8*)(qpB + ks * 32 + lg * 8);
    }
  }
  f32x4 ofA[8] = {}, ofB[8] = {};
  float mA[4], lA[4], mB[4], lB[4];
#pragma unroll
  for (int j = 0; j < 4; ++j) { mA[j] = mB[j] = -1e30f; lA[j] = lB[j] = 0.f; }
  const int myqA = q0A + w * 16 + lg * 4;
  const int myqB = q0B + w * 16 + lg * 4;
  char* pw = (char*)&Ps[w][0];

  for (int t = 0; t < ntB; ++t) {
    const int kv0 = t * 128;
#pragma unroll
    for (int it = 0; it < 8; ++it) {
      int g = it * 256 + tid;
      int r = g >> 4, sl = g & 15;
      int ssl = sl ^ (r & 7);
      gload_lds16(qkv + (size_t)(b * SEQ + kv0 + r) * NQKV + DM + h * DH + ssl * 8,
                  (char*)Ks + (size_t)g * 16);
    }
#pragma unroll
    for (int it = 0; it < 8; ++it) {
      int g = it * 256 + tid;
      int r = g >> 4, sl = g & 15;
      int ssl = sl ^ (r & 7);
      gload_lds16(vT + (size_t)(bh * DH + r) * SEQ + kv0 + ssl * 8,
                  (char*)Vs + (size_t)g * 16);
    }
    __syncthreads();
    if (t < ntA)
      attn_tile(qfA, ofA, mA, lA, (const char*)Ks, (const char*)Vs, pw,
                lr, lg, kv0, myqA, t == ntA - 1, scale);
    attn_tile(qfB, ofB, mB, lB, (const char*)Ks, (const char*)Vs, pw,
              lr, lg, kv0, myqB, t == ntB - 1, scale);
    __syncthreads();
  }
#pragma unroll
  for (int j = 0; j < 4; ++j) {
    float invA = 1.0f / lA[j], invB = 1.0f / lB[j];
    __hip_bfloat16* opA =
        O + (size_t)(b * SEQ + q0A + w * 16 + lg * 4 + j) * DM + h * DH;
    __hip_bfloat16* opB =
        O + (size_t)(b * SEQ + q0B + w * 16 + lg * 4 + j) * DM + h * DH;
#pragma unroll
    for (int nn = 0; nn < 8; ++nn) {
      opA[nn * 16 + lr] = __float2bfloat16(ofA[nn][j] * invA);
      opB[nn * 16 + lr] = __float2bfloat16(ofB[nn][j] * invB);
    }
  }
}

extern "C" void kernel_launch(void* const* d_in, const int* in_sizes, int n_in,
                              void* d_out, int out_size, void* d_ws, size_t ws_size,
                              hipStream_t stream) {
  const float* x = (const float*)d_in[0];
  const float* Wqkv = (const float*)d_in[1];
  const float* Wout = (const float*)d_in[2];
  float* out = (float*)d_out;
  char* ws = (char*)d_ws;
  __hip_bfloat16* xb    = (__hip_bfloat16*)(ws + 0);
  __hip_bfloat16* wqkvT = (__hip_bfloat16*)(ws + (size_t)16777216);
  __hip_bfloat16* woutT = (__hip_bfloat16*)(ws + (size_t)41943040);
  __hip_bfloat16* qkvb  = (__hip_bfloat16*)(ws + (size_t)50331648);
  __hip_bfloat16* vT    = (__hip_bfloat16*)(ws + (size_t)100663296);
  __hip_bfloat16* ob    = (__hip_bfloat16*)(ws + (size_t)117440512);

  cast_f32_bf16<<<dim3(8192), dim3(256), 0, stream>>>(x, xb, 8388608 / 4);
  transpose_cast<<<dim3(192, 64), dim3(32, 8), 0, stream>>>(Wqkv, wqkvT, 2048, 6144);
  transpose_cast<<<dim3(64, 64), dim3(32, 8), 0, stream>>>(Wout, woutT, 2048, 2048);
  gemm256<0><<<dim3(384), dim3(512), 0, stream>>>(xb, wqkvT, qkvb, 4096, 6144, 2048);
  transpose_v<<<dim3(64, 4, 32), dim3(32, 8), 0, stream>>>(qkvb, vT);
  attn_causal<<<dim3(16, 32), dim3(256), 0, stream>>>(qkvb, vT, ob);
  gemm256<1><<<dim3(128), dim3(512), 0, stream>>>(ob, woutT, out, 4096, 2048, 2048);
}